// Round 2
// baseline (128.878 us; speedup 1.0000x reference)
//
#include <hip/hip_runtime.h>

#define HSZ 128
#define ISZ 28
#define TSZ 28
#define CSZ 10
#define BT  32     // batch rows per block = 2 MFMA col-groups of 16
#define NG  2      // batch groups per wave
#define NT  512    // 8 waves, one 16-row hidden tile each, x NG batch groups
#define HP  136    // h row stride in halves
#define XP  32     // x row stride in halves (K padded 28->32)

typedef _Float16 half_t;
typedef _Float16 v8h __attribute__((ext_vector_type(8)));
typedef _Float16 v4h __attribute__((ext_vector_type(4)));
typedef float v4f __attribute__((ext_vector_type(4)));

__device__ __forceinline__ float fast_tanh(float x) {
    // 1 - 2/(e^{2x}+1); saturates correctly (+-inf -> +-1)
    float e = __expf(2.f * x);
    return 1.f - 2.f * __builtin_amdgcn_rcpf(e + 1.f);
}

// MFMA 16x16x32 f16 layouts (HW-verified):
//   A-frag: lane holds A[m = lane&15][k = (lane>>4)*8 + j], j=0..7
//   B-frag: lane holds B[k = (lane>>4)*8 + j][n = lane&15]
//   C/D   : lane holds D[row = (lane>>4)*4 + r][col = lane&15], r=0..3
// G = W · h^T: A = weight tile (rows = hidden units), B[k][n] = h[batch n][k].
__global__ __launch_bounds__(NT, 2)   // 1 block/CU (grid == #CU); VGPR headroom
void rnn_mfma5(const float* __restrict__ x,
               const float* __restrict__ W_ih0, const float* __restrict__ W_hh0,
               const float* __restrict__ b_ih0, const float* __restrict__ b_hh0,
               const float* __restrict__ W_ih1, const float* __restrict__ W_hh1,
               const float* __restrict__ b_ih1, const float* __restrict__ b_hh1,
               const float* __restrict__ fc_w, const float* __restrict__ fc_b,
               float* __restrict__ out)
{
    __shared__ half_t h0s[2][BT * HP];    // 17.4 KB each
    __shared__ half_t h1s[2][BT * HP];
    __shared__ half_t xs[TSZ][BT * XP];   // all timesteps staged once: 57.3 KB

    const int tid  = threadIdx.x;
    const int wave = tid >> 6;          // 0..7 -> row-tile [wave*16, wave*16+16)
    const int lane = tid & 63;
    const int ln   = lane & 15;
    const int quad = lane >> 4;
    const int kq   = quad * 8;
    const int b0   = blockIdx.x * BT;
    const int base = wave * 16;
    const int row  = base + ln;         // A-frag row (hidden unit)

    // ---- persistent weight A-fragments (loaded once): 13 frags ----
    v8h aWx, aW0[4], aW1i[4], aW1h[4];
    v4f bias0, bias1;
    {
        float4 p = *(const float4*)(b_ih0 + base + quad * 4);
        float4 q = *(const float4*)(b_hh0 + base + quad * 4);
        bias0 = (v4f){p.x + q.x, p.y + q.y, p.z + q.z, p.w + q.w};
        p = *(const float4*)(b_ih1 + base + quad * 4);
        q = *(const float4*)(b_hh1 + base + quad * 4);
        bias1 = (v4f){p.x + q.x, p.y + q.y, p.z + q.z, p.w + q.w};
    }
    {
        const float* pw = W_ih0 + row * ISZ + kq;      // kq<=24, kq+3<=27 in-row
        float4 a = *(const float4*)pw;
        float4 b = (kq < 24) ? *(const float4*)(pw + 4) : make_float4(0.f, 0.f, 0.f, 0.f);
        aWx = (v8h){(half_t)a.x, (half_t)a.y, (half_t)a.z, (half_t)a.w,
                    (half_t)b.x, (half_t)b.y, (half_t)b.z, (half_t)b.w};
    }
#pragma unroll
    for (int ks = 0; ks < 4; ++ks) {
        const float4* p0 = (const float4*)(W_hh0 + row * HSZ + ks * 32 + kq);
        const float4* p1 = (const float4*)(W_ih1 + row * HSZ + ks * 32 + kq);
        const float4* p2 = (const float4*)(W_hh1 + row * HSZ + ks * 32 + kq);
        float4 a = p0[0], b = p0[1];
        aW0[ks] = (v8h){(half_t)a.x, (half_t)a.y, (half_t)a.z, (half_t)a.w,
                        (half_t)b.x, (half_t)b.y, (half_t)b.z, (half_t)b.w};
        a = p1[0]; b = p1[1];
        aW1i[ks] = (v8h){(half_t)a.x, (half_t)a.y, (half_t)a.z, (half_t)a.w,
                         (half_t)b.x, (half_t)b.y, (half_t)b.z, (half_t)b.w};
        a = p2[0]; b = p2[1];
        aW1h[ks] = (v8h){(half_t)a.x, (half_t)a.y, (half_t)a.z, (half_t)a.w,
                         (half_t)b.x, (half_t)b.y, (half_t)b.z, (half_t)b.w};
    }

    // ---- stage ALL x for this block's 32 rows as f16, coalesced float4 ----
    // 32 rows x 196 float4/row = 6272 float4. 28 % 4 == 0 -> no straddle.
    {
        const float* xblk = x + (size_t)b0 * (TSZ * ISZ);
#pragma unroll
        for (int k = 0; k < 13; ++k) {
            const int F = tid + k * NT;
            if (F < BT * 196) {
                const int r   = F / 196;
                const int rem = F - r * 196;
                const int t   = rem / 7;
                const int i4  = (rem - t * 7) * 4;
                const float4 v = *(const float4*)(xblk + r * (TSZ * ISZ) + rem * 4);
                v4h p = {(half_t)v.x, (half_t)v.y, (half_t)v.z, (half_t)v.w};
                *(v4h*)&xs[t][r * XP + i4] = p;
            }
        }
        // zero the K-pad (cols 28..31)
        for (int idx = tid; idx < TSZ * BT; idx += NT) {
            const int tt = idx >> 5, rr = idx & 31;
            *(v4h*)&xs[tt][rr * XP + ISZ] =
                (v4h){(half_t)0.f, (half_t)0.f, (half_t)0.f, (half_t)0.f};
        }
    }

    for (int idx = tid; idx < BT * HP; idx += NT)
        h1s[0][idx] = (half_t)0.f;              // h1(-1) = 0
    __syncthreads();

    // ---- h0(0) = tanh(W_ih0 x0^T + b0) -> h0s[0], both batch groups ----
#pragma unroll
    for (int g = 0; g < NG; ++g) {
        const v8h bx = *(const v8h*)&xs[0][(g * 16 + ln) * XP + kq];
        v4f a0 = bias0;
        a0 = __builtin_amdgcn_mfma_f32_16x16x32_f16(aWx, bx, a0, 0, 0, 0);
        v4h p = {(half_t)fast_tanh(a0[0]), (half_t)fast_tanh(a0[1]),
                 (half_t)fast_tanh(a0[2]), (half_t)fast_tanh(a0[3])};
        *(v4h*)&h0s[0][(g * 16 + ln) * HP + base + quad * 4] = p;
    }
    __syncthreads();

    // ---- main loop: segment t computes h1(t) and h0(t+1), 2 groups/wave ----
#pragma unroll 2
    for (int t = 0; t < TSZ - 1; ++t) {
        const int pr = t & 1;

        // B-fragments: h0 + x first (layer-0 recurrence is the critical path)
        v8h bh0[NG][4], bh1[NG][4], bx[NG];
#pragma unroll
        for (int g = 0; g < NG; ++g) {
#pragma unroll
            for (int ks = 0; ks < 4; ++ks)
                bh0[g][ks] = *(const v8h*)&h0s[pr][(g * 16 + ln) * HP + ks * 32 + kq];
            bx[g] = *(const v8h*)&xs[t + 1][(g * 16 + ln) * XP + kq];
        }
#pragma unroll
        for (int g = 0; g < NG; ++g)
#pragma unroll
            for (int ks = 0; ks < 4; ++ks)
                bh1[g][ks] = *(const v8h*)&h1s[pr][(g * 16 + ln) * HP + ks * 32 + kq];

        // ---- layer 0 (recurrence-critical): shallow chains, commit early ----
#pragma unroll
        for (int g = 0; g < NG; ++g) {
            v4f c0 = bias0;
            c0 = __builtin_amdgcn_mfma_f32_16x16x32_f16(aWx, bx[g], c0, 0, 0, 0);
            v4f c1 = (v4f){0.f, 0.f, 0.f, 0.f};
            c1 = __builtin_amdgcn_mfma_f32_16x16x32_f16(aW0[0], bh0[g][0], c1, 0, 0, 0);
            c1 = __builtin_amdgcn_mfma_f32_16x16x32_f16(aW0[1], bh0[g][1], c1, 0, 0, 0);
            v4f c2 = (v4f){0.f, 0.f, 0.f, 0.f};
            c2 = __builtin_amdgcn_mfma_f32_16x16x32_f16(aW0[2], bh0[g][2], c2, 0, 0, 0);
            c2 = __builtin_amdgcn_mfma_f32_16x16x32_f16(aW0[3], bh0[g][3], c2, 0, 0, 0);
            const v4f a0 = c0 + c1 + c2;
            v4h p0 = {(half_t)fast_tanh(a0[0]), (half_t)fast_tanh(a0[1]),
                      (half_t)fast_tanh(a0[2]), (half_t)fast_tanh(a0[3])};
            *(v4h*)&h0s[pr ^ 1][(g * 16 + ln) * HP + base + quad * 4] = p0;
        }

        // ---- layer 1: four depth-2 chains per group ----
#pragma unroll
        for (int g = 0; g < NG; ++g) {
            v4f s0 = bias1;
            s0 = __builtin_amdgcn_mfma_f32_16x16x32_f16(aW1i[0], bh0[g][0], s0, 0, 0, 0);
            s0 = __builtin_amdgcn_mfma_f32_16x16x32_f16(aW1i[1], bh0[g][1], s0, 0, 0, 0);
            v4f s1 = (v4f){0.f, 0.f, 0.f, 0.f};
            s1 = __builtin_amdgcn_mfma_f32_16x16x32_f16(aW1i[2], bh0[g][2], s1, 0, 0, 0);
            s1 = __builtin_amdgcn_mfma_f32_16x16x32_f16(aW1i[3], bh0[g][3], s1, 0, 0, 0);
            v4f s2 = (v4f){0.f, 0.f, 0.f, 0.f};
            s2 = __builtin_amdgcn_mfma_f32_16x16x32_f16(aW1h[0], bh1[g][0], s2, 0, 0, 0);
            s2 = __builtin_amdgcn_mfma_f32_16x16x32_f16(aW1h[1], bh1[g][1], s2, 0, 0, 0);
            v4f s3 = (v4f){0.f, 0.f, 0.f, 0.f};
            s3 = __builtin_amdgcn_mfma_f32_16x16x32_f16(aW1h[2], bh1[g][2], s3, 0, 0, 0);
            s3 = __builtin_amdgcn_mfma_f32_16x16x32_f16(aW1h[3], bh1[g][3], s3, 0, 0, 0);
            const v4f a1 = (s0 + s1) + (s2 + s3);
            v4h p1 = {(half_t)fast_tanh(a1[0]), (half_t)fast_tanh(a1[1]),
                      (half_t)fast_tanh(a1[2]), (half_t)fast_tanh(a1[3])};
            *(v4h*)&h1s[pr ^ 1][(g * 16 + ln) * HP + base + quad * 4] = p1;
        }

        __syncthreads();
    }

    // ---- final segment: h1(27) only -> h1s[0], both groups ----
    {
        const int pr = (TSZ - 1) & 1;   // = 1
#pragma unroll
        for (int g = 0; g < NG; ++g) {
            v4f s0 = bias1;
            v4f s2 = (v4f){0.f, 0.f, 0.f, 0.f};
#pragma unroll
            for (int ks = 0; ks < 4; ++ks) {
                const v8h bh0 = *(const v8h*)&h0s[pr][(g * 16 + ln) * HP + ks * 32 + kq];
                const v8h bh1 = *(const v8h*)&h1s[pr][(g * 16 + ln) * HP + ks * 32 + kq];
                s0 = __builtin_amdgcn_mfma_f32_16x16x32_f16(aW1i[ks], bh0, s0, 0, 0, 0);
                s2 = __builtin_amdgcn_mfma_f32_16x16x32_f16(aW1h[ks], bh1, s2, 0, 0, 0);
            }
            const v4f a1 = s0 + s2;
            v4h p1 = {(half_t)fast_tanh(a1[0]), (half_t)fast_tanh(a1[1]),
                      (half_t)fast_tanh(a1[2]), (half_t)fast_tanh(a1[3])};
            *(v4h*)&h1s[pr ^ 1][(g * 16 + ln) * HP + base + quad * 4] = p1;
        }
    }
    __syncthreads();

    // ---- FC epilogue: out = h1(27) @ fc_w^T + fc_b ----
    if (tid < BT * CSZ) {
        const int m = tid / CSZ, cc = tid - m * CSZ;
        float s = fc_b[cc];
#pragma unroll
        for (int k8 = 0; k8 < HSZ / 8; ++k8) {
            const v8h hv = *(const v8h*)&h1s[0][m * HP + k8 * 8];
            const float4 w0 = *(const float4*)(fc_w + cc * HSZ + k8 * 8);
            const float4 w1 = *(const float4*)(fc_w + cc * HSZ + k8 * 8 + 4);
            s += (float)hv[0] * w0.x + (float)hv[1] * w0.y +
                 (float)hv[2] * w0.z + (float)hv[3] * w0.w +
                 (float)hv[4] * w1.x + (float)hv[5] * w1.y +
                 (float)hv[6] * w1.z + (float)hv[7] * w1.w;
        }
        out[(b0 + m) * CSZ + cc] = s;
    }
}

extern "C" void kernel_launch(void* const* d_in, const int* in_sizes, int n_in,
                              void* d_out, int out_size, void* d_ws, size_t ws_size,
                              hipStream_t stream) {
    const float* x     = (const float*)d_in[0];
    const float* W_ih0 = (const float*)d_in[1];
    const float* W_hh0 = (const float*)d_in[2];
    const float* b_ih0 = (const float*)d_in[3];
    const float* b_hh0 = (const float*)d_in[4];
    const float* W_ih1 = (const float*)d_in[5];
    const float* W_hh1 = (const float*)d_in[6];
    const float* b_ih1 = (const float*)d_in[7];
    const float* b_hh1 = (const float*)d_in[8];
    const float* fc_w  = (const float*)d_in[9];
    const float* fc_b  = (const float*)d_in[10];
    float* out = (float*)d_out;

    const int B = in_sizes[0] / (TSZ * ISZ);   // 8192
    dim3 grid(B / BT), block(NT);
    rnn_mfma5<<<grid, block, 0, stream>>>(x, W_ih0, W_hh0, b_ih0, b_hh0,
                                          W_ih1, W_hh1, b_ih1, b_hh1,
                                          fc_w, fc_b, out);
}

// Round 3
// 128.141 us; speedup vs baseline: 1.0058x; 1.0058x over previous
//
#include <hip/hip_runtime.h>

#define HSZ 128
#define ISZ 28
#define TSZ 28
#define CSZ 10
#define BT  16     // batch rows per block
#define NT  256    // 4 waves, each owns 32 hidden units (2 row-tiles)
#define HBUF 2048  // halves per h buffer: 4 ks * 64 lanes * 8

typedef _Float16 half_t;
typedef _Float16 v8h __attribute__((ext_vector_type(8)));
typedef _Float16 v4h __attribute__((ext_vector_type(4)));
typedef float v4f __attribute__((ext_vector_type(4)));

__device__ __forceinline__ float fast_tanh(float x) {
    // 1 - 2/(e^{2x}+1); saturates correctly (+-inf -> +-1)
    float e = __expf(2.f * x);
    return 1.f - 2.f * __builtin_amdgcn_rcpf(e + 1.f);
}

// MFMA 16x16x32 f16 layouts (HW-verified):
//   A-frag: lane holds A[m = lane&15][k = (lane>>4)*8 + j], j=0..7
//   B-frag: lane holds B[k = (lane>>4)*8 + j][n = lane&15]
//   C/D   : lane holds D[row = (lane>>4)*4 + r][col = lane&15], r=0..3
//
// h/x LDS layout is FRAGMENT-LINEAR: element (k, n) lives at
//   half-index ((k>>5)*64 + ((k>>3)&3)*16 + n)*8 + (k&7)
// so a B-frag for k-slice ks is one conflict-free ds_read_b128 at
//   (ks*64 + lane)*8  (each lane reads its own contiguous 16B).
__global__ __launch_bounds__(NT, 2)   // VGPR<=256 -> 2 waves/SIMD, 2 blocks/CU
void rnn_mfma6(const float* __restrict__ x,
               const float* __restrict__ W_ih0, const float* __restrict__ W_hh0,
               const float* __restrict__ b_ih0, const float* __restrict__ b_hh0,
               const float* __restrict__ W_ih1, const float* __restrict__ W_hh1,
               const float* __restrict__ b_ih1, const float* __restrict__ b_hh1,
               const float* __restrict__ fc_w, const float* __restrict__ fc_b,
               float* __restrict__ out)
{
    __shared__ half_t h0s[2][HBUF];       // 8 KB
    __shared__ half_t h1s[2][HBUF];       // 8 KB
    __shared__ half_t xs[TSZ][512];       // 28 KB, frag-linear per timestep

    const int tid  = threadIdx.x;
    const int wave = tid >> 6;            // 0..3 -> hidden units [wave*32, +32)
    const int lane = tid & 63;
    const int ln   = lane & 15;
    const int quad = lane >> 4;
    const int b0   = blockIdx.x * BT;
    const int wbase = wave * 32;

    // ---- persistent weight A-fragments: 26 frags = 104 VGPR ----
    v8h aWx[2], aW0[2][4], aW1i[2][4], aW1h[2][4];
    v4f bias0[2], bias1[2];
#pragma unroll
    for (int rt = 0; rt < 2; ++rt) {
        const int row = wbase + rt * 16 + ln;     // A-frag row (hidden unit)
        {
            float4 p = *(const float4*)(b_ih0 + wbase + rt * 16 + quad * 4);
            float4 q = *(const float4*)(b_hh0 + wbase + rt * 16 + quad * 4);
            bias0[rt] = (v4f){p.x + q.x, p.y + q.y, p.z + q.z, p.w + q.w};
            p = *(const float4*)(b_ih1 + wbase + rt * 16 + quad * 4);
            q = *(const float4*)(b_hh1 + wbase + rt * 16 + quad * 4);
            bias1[rt] = (v4f){p.x + q.x, p.y + q.y, p.z + q.z, p.w + q.w};
        }
        {
            const float* pw = W_ih0 + row * ISZ + quad * 8;
            float4 a = *(const float4*)pw;
            float4 b = (quad < 3) ? *(const float4*)(pw + 4) : make_float4(0.f, 0.f, 0.f, 0.f);
            aWx[rt] = (v8h){(half_t)a.x, (half_t)a.y, (half_t)a.z, (half_t)a.w,
                            (half_t)b.x, (half_t)b.y, (half_t)b.z, (half_t)b.w};
        }
#pragma unroll
        for (int ks = 0; ks < 4; ++ks) {
            const float4* p0 = (const float4*)(W_hh0 + row * HSZ + ks * 32 + quad * 8);
            const float4* p1 = (const float4*)(W_ih1 + row * HSZ + ks * 32 + quad * 8);
            const float4* p2 = (const float4*)(W_hh1 + row * HSZ + ks * 32 + quad * 8);
            float4 a = p0[0], b = p0[1];
            aW0[rt][ks] = (v8h){(half_t)a.x, (half_t)a.y, (half_t)a.z, (half_t)a.w,
                                (half_t)b.x, (half_t)b.y, (half_t)b.z, (half_t)b.w};
            a = p1[0]; b = p1[1];
            aW1i[rt][ks] = (v8h){(half_t)a.x, (half_t)a.y, (half_t)a.z, (half_t)a.w,
                                 (half_t)b.x, (half_t)b.y, (half_t)b.z, (half_t)b.w};
            a = p2[0]; b = p2[1];
            aW1h[rt][ks] = (v8h){(half_t)a.x, (half_t)a.y, (half_t)a.z, (half_t)a.w,
                                 (half_t)b.x, (half_t)b.y, (half_t)b.z, (half_t)b.w};
        }
    }

    // ---- stage ALL x as f16 in frag-linear form: chunk c -> (t, n, q) ----
    // lane-chunk (q*16+n) of xs[t] holds x[b0+n][t][q*8 .. q*8+7] (pad -> 0).
    // q fastest in c => 4 consecutive tids read 128B contiguous global.
    {
#pragma unroll
        for (int it = 0; it < 7; ++it) {
            const int c = tid + it * NT;          // < 1792 always
            const int q = c & 3;
            const int n = (c >> 2) & 15;
            const int t = c >> 6;
            const float* g = x + ((size_t)(b0 + n) * TSZ + t) * ISZ + q * 8;
            float4 a = *(const float4*)g;
            float4 b = (q < 3) ? *(const float4*)(g + 4) : make_float4(0.f, 0.f, 0.f, 0.f);
            v8h p = {(half_t)a.x, (half_t)a.y, (half_t)a.z, (half_t)a.w,
                     (half_t)b.x, (half_t)b.y, (half_t)b.z, (half_t)b.w};
            *(v8h*)&xs[t][(q * 16 + n) * 8] = p;
        }
    }

    // zero h1(-1)
    *(v8h*)&h1s[0][tid * 8] = (v8h){(half_t)0.f, (half_t)0.f, (half_t)0.f, (half_t)0.f,
                                    (half_t)0.f, (half_t)0.f, (half_t)0.f, (half_t)0.f};
    __syncthreads();

    // write slots (loop-invariant): unit u = wbase + rt*16 + quad*4 + r
    //   -> half-idx wave*512 + rt*256 + (quad>>1)*128 + ln*8 + (quad&1)*4
    const int ws0 = wave * 512 + (quad >> 1) * 128 + ln * 8 + (quad & 1) * 4;
    const int ws1 = ws0 + 256;
    // read offsets
    const int ro = lane * 8;                      // + ks*512

    // ---- h0(0) = tanh(W_ih0 x0^T + b0) ----
    {
        const v8h bx = *(const v8h*)&xs[0][ro];
#pragma unroll
        for (int rt = 0; rt < 2; ++rt) {
            v4f c = bias0[rt];
            c = __builtin_amdgcn_mfma_f32_16x16x32_f16(aWx[rt], bx, c, 0, 0, 0);
            v4h p = {(half_t)fast_tanh(c[0]), (half_t)fast_tanh(c[1]),
                     (half_t)fast_tanh(c[2]), (half_t)fast_tanh(c[3])};
            *(v4h*)&h0s[0][rt ? ws1 : ws0] = p;
        }
    }
    __syncthreads();

    // ---- main loop: segment t computes h1(t) and h0(t+1) ----
#pragma unroll 2
    for (int t = 0; t < TSZ - 1; ++t) {
        const int pr = t & 1;

        v8h bh0[4], bh1[4];
#pragma unroll
        for (int ks = 0; ks < 4; ++ks)
            bh0[ks] = *(const v8h*)&h0s[pr][ks * 512 + ro];
        const v8h bx = *(const v8h*)&xs[t + 1][ro];
#pragma unroll
        for (int ks = 0; ks < 4; ++ks)
            bh1[ks] = *(const v8h*)&h1s[pr][ks * 512 + ro];

        // layer 0: two independent depth-5 chains
#pragma unroll
        for (int rt = 0; rt < 2; ++rt) {
            v4f c = bias0[rt];
            c = __builtin_amdgcn_mfma_f32_16x16x32_f16(aWx[rt], bx, c, 0, 0, 0);
#pragma unroll
            for (int ks = 0; ks < 4; ++ks)
                c = __builtin_amdgcn_mfma_f32_16x16x32_f16(aW0[rt][ks], bh0[ks], c, 0, 0, 0);
            v4h p = {(half_t)fast_tanh(c[0]), (half_t)fast_tanh(c[1]),
                     (half_t)fast_tanh(c[2]), (half_t)fast_tanh(c[3])};
            *(v4h*)&h0s[pr ^ 1][rt ? ws1 : ws0] = p;
        }

        // layer 1: per rt, two depth-4 chains + add
#pragma unroll
        for (int rt = 0; rt < 2; ++rt) {
            v4f si = bias1[rt];
            v4f sh = (v4f){0.f, 0.f, 0.f, 0.f};
#pragma unroll
            for (int ks = 0; ks < 4; ++ks) {
                si = __builtin_amdgcn_mfma_f32_16x16x32_f16(aW1i[rt][ks], bh0[ks], si, 0, 0, 0);
                sh = __builtin_amdgcn_mfma_f32_16x16x32_f16(aW1h[rt][ks], bh1[ks], sh, 0, 0, 0);
            }
            const v4f a1 = si + sh;
            v4h p = {(half_t)fast_tanh(a1[0]), (half_t)fast_tanh(a1[1]),
                     (half_t)fast_tanh(a1[2]), (half_t)fast_tanh(a1[3])};
            *(v4h*)&h1s[pr ^ 1][rt ? ws1 : ws0] = p;
        }

        __syncthreads();
    }

    // ---- final segment: h1(27) only -> h1s[0] ----
    {
        const int pr = (TSZ - 1) & 1;   // = 1
        v8h bh0[4], bh1[4];
#pragma unroll
        for (int ks = 0; ks < 4; ++ks) {
            bh0[ks] = *(const v8h*)&h0s[pr][ks * 512 + ro];
            bh1[ks] = *(const v8h*)&h1s[pr][ks * 512 + ro];
        }
#pragma unroll
        for (int rt = 0; rt < 2; ++rt) {
            v4f si = bias1[rt];
            v4f sh = (v4f){0.f, 0.f, 0.f, 0.f};
#pragma unroll
            for (int ks = 0; ks < 4; ++ks) {
                si = __builtin_amdgcn_mfma_f32_16x16x32_f16(aW1i[rt][ks], bh0[ks], si, 0, 0, 0);
                sh = __builtin_amdgcn_mfma_f32_16x16x32_f16(aW1h[rt][ks], bh1[ks], sh, 0, 0, 0);
            }
            const v4f a1 = si + sh;
            v4h p = {(half_t)fast_tanh(a1[0]), (half_t)fast_tanh(a1[1]),
                     (half_t)fast_tanh(a1[2]), (half_t)fast_tanh(a1[3])};
            *(v4h*)&h1s[pr ^ 1][rt ? ws1 : ws0] = p;
        }
    }
    __syncthreads();

    // ---- FC epilogue: out = h1(27) @ fc_w^T + fc_b ----
    // h1 frag-linear: k = ks*32 + q2*8 + j at [(ks*64 + q2*16 + m)*8 + j]
    if (tid < BT * CSZ) {
        const int m = tid / CSZ, cc = tid - m * CSZ;
        float s = fc_b[cc];
#pragma unroll
        for (int ks = 0; ks < 4; ++ks) {
#pragma unroll
            for (int q2 = 0; q2 < 4; ++q2) {
                const v8h hv = *(const v8h*)&h1s[0][(ks * 64 + q2 * 16 + m) * 8];
                const int kb = ks * 32 + q2 * 8;
                const float4 w0 = *(const float4*)(fc_w + cc * HSZ + kb);
                const float4 w1 = *(const float4*)(fc_w + cc * HSZ + kb + 4);
                s += (float)hv[0] * w0.x + (float)hv[1] * w0.y +
                     (float)hv[2] * w0.z + (float)hv[3] * w0.w +
                     (float)hv[4] * w1.x + (float)hv[5] * w1.y +
                     (float)hv[6] * w1.z + (float)hv[7] * w1.w;
            }
        }
        out[(b0 + m) * CSZ + cc] = s;
    }
}

extern "C" void kernel_launch(void* const* d_in, const int* in_sizes, int n_in,
                              void* d_out, int out_size, void* d_ws, size_t ws_size,
                              hipStream_t stream) {
    const float* x     = (const float*)d_in[0];
    const float* W_ih0 = (const float*)d_in[1];
    const float* W_hh0 = (const float*)d_in[2];
    const float* b_ih0 = (const float*)d_in[3];
    const float* b_hh0 = (const float*)d_in[4];
    const float* W_ih1 = (const float*)d_in[5];
    const float* W_hh1 = (const float*)d_in[6];
    const float* b_ih1 = (const float*)d_in[7];
    const float* b_hh1 = (const float*)d_in[8];
    const float* fc_w  = (const float*)d_in[9];
    const float* fc_b  = (const float*)d_in[10];
    float* out = (float*)d_out;

    const int B = in_sizes[0] / (TSZ * ISZ);   // 8192
    dim3 grid(B / BT), block(NT);
    rnn_mfma6<<<grid, block, 0, stream>>>(x, W_ih0, W_hh0, b_ih0, b_hh0,
                                          W_ih1, W_hh1, b_ih1, b_hh1,
                                          fc_w, fc_b, out);
}